// Round 1
// baseline (449.286 us; speedup 1.0000x reference)
//
#include <hip/hip_runtime.h>
#include <hip/hip_bf16.h>
#include <stdint.h>

#define BATCH_N 65536
#define KDIM 1024
#define NTOT 1536

typedef __bf16 bf16x8 __attribute__((ext_vector_type(8)));
typedef float f32x4 __attribute__((ext_vector_type(4)));

__device__ __forceinline__ unsigned short f2bf(float f) {
    unsigned u = __builtin_bit_cast(unsigned, f);
    u += 0x7FFFu + ((u >> 16) & 1u);   // round-to-nearest-even
    return (unsigned short)(u >> 16);
}

// ---------------------------------------------------------------------------
// Kernel 1: x[b][k] = sum_k(node_memories[id]) + node_embedding[id][k], bf16,
// stored pre-swizzled (k ^= (b&7)<<3) so linear global_load_lds staging in the
// GEMM produces a bank-conflict-free LDS layout.
// ---------------------------------------------------------------------------
__global__ __launch_bounds__(256) void prep_kernel(
    const int* __restrict__ ids,
    const float* __restrict__ mem,
    const float* __restrict__ emb,
    unsigned short* __restrict__ x)
{
    const int b = blockIdx.x;
    const int t = threadIdx.x;
    const int id = ids[b];
    const float4* m4 = (const float4*)(mem + (size_t)id * KDIM);
    const float4* e4 = (const float4*)(emb + (size_t)id * KDIM);
    float4 v = m4[t];
    float s = v.x + v.y + v.z + v.w;
    #pragma unroll
    for (int off = 32; off >= 1; off >>= 1) s += __shfl_down(s, off, 64);
    __shared__ float wsum[4];
    const int lane = t & 63, w = t >> 6;
    if (lane == 0) wsum[w] = s;
    __syncthreads();
    const float tot = wsum[0] + wsum[1] + wsum[2] + wsum[3];
    float4 e = e4[t];
    ushort4 o;
    o.x = f2bf(tot + e.x);
    o.y = f2bf(tot + e.y);
    o.z = f2bf(tot + e.z);
    o.w = f2bf(tot + e.w);
    const int k   = t * 4;
    const int ksw = k ^ ((b & 7) << 3);
    *(ushort4*)(x + (size_t)b * KDIM + ksw) = o;
}

// ---------------------------------------------------------------------------
// Kernel 2: Wt[n][k] = W_{n/512}[k][n%512] in bf16, same pre-swizzle on k.
// n-major layout makes the B fragment load identical in form to A's.
// ---------------------------------------------------------------------------
__global__ __launch_bounds__(256) void wconv_kernel(
    const float* __restrict__ Wq, const float* __restrict__ Ws,
    const float* __restrict__ Wk, unsigned short* __restrict__ wt)
{
    const int gt = blockIdx.x * 256 + threadIdx.x;   // 0..393215
    const int n  = gt % NTOT;
    const int kb = (gt / NTOT) * 4;
    const float* W = (n < 512) ? Wq : ((n < 1024) ? Ws : Wk);
    const int nn = n & 511;
    ushort4 o;
    o.x = f2bf(W[(size_t)(kb + 0) * 512 + nn]);
    o.y = f2bf(W[(size_t)(kb + 1) * 512 + nn]);
    o.z = f2bf(W[(size_t)(kb + 2) * 512 + nn]);
    o.w = f2bf(W[(size_t)(kb + 3) * 512 + nn]);
    const int ksw = kb ^ ((n & 7) << 3);
    *(ushort4*)(wt + (size_t)n * KDIM + ksw) = o;
}

// ---------------------------------------------------------------------------
// Kernel 3: C[m][n] = sigmoid(x @ W + b), 128x128 tile, BK=64, 4 waves,
// mfma_f32_16x16x32_bf16, global_load_lds(16B) staging, swizzled LDS.
// ---------------------------------------------------------------------------
#define BM 128
#define BN 128
#define BK 64

__global__ __launch_bounds__(256, 2) void gemm_kernel(
    const unsigned short* __restrict__ X,    // [65536][1024] bf16, swizzled
    const unsigned short* __restrict__ Wt,   // [1536][1024]  bf16, swizzled
    const float* __restrict__ bq, const float* __restrict__ bs,
    const float* __restrict__ bk, float* __restrict__ out)
{
    __shared__ __align__(16) unsigned short lA[BM * BK];  // 16 KiB
    __shared__ __align__(16) unsigned short lB[BN * BK];  // 16 KiB

    const int tid  = threadIdx.x;
    const int mt   = blockIdx.x & 511;   // m fastest: stream x, reuse W tile
    const int nt   = blockIdx.x >> 9;
    const int m0   = mt * BM;
    const int n0   = nt * BN;
    const int wid  = tid >> 6;
    const int lane = tid & 63;
    const int wr   = wid >> 1, wc = wid & 1;

    f32x4 acc[4][4];
    #pragma unroll
    for (int i = 0; i < 4; i++)
        #pragma unroll
        for (int j = 0; j < 4; j++)
            acc[i][j] = f32x4{0.f, 0.f, 0.f, 0.f};

    // staging: linear index li = issue*256 + tid ; row = li>>3 ; 16B chunk = li&7
    const unsigned short* gA = X  + (size_t)(m0 + (tid >> 3)) * KDIM + (size_t)(tid & 7) * 8;
    const unsigned short* gB = Wt + (size_t)(n0 + (tid >> 3)) * KDIM + (size_t)(tid & 7) * 8;

    for (int ks = 0; ks < KDIM; ks += BK) {
        __syncthreads();
        #pragma unroll
        for (int i = 0; i < 4; i++) {
            __builtin_amdgcn_global_load_lds(
                (const __attribute__((address_space(1))) void*)(gA + (size_t)i * 32 * KDIM + ks),
                (__attribute__((address_space(3))) void*)(&lA[(i * 256 + (tid & 192)) * 8]),
                16, 0, 0);
        }
        #pragma unroll
        for (int i = 0; i < 4; i++) {
            __builtin_amdgcn_global_load_lds(
                (const __attribute__((address_space(1))) void*)(gB + (size_t)i * 32 * KDIM + ks),
                (__attribute__((address_space(3))) void*)(&lB[(i * 256 + (tid & 192)) * 8]),
                16, 0, 0);
        }
        __syncthreads();

        #pragma unroll
        for (int kk = 0; kk < 2; kk++) {
            const int r16  = lane & 15;
            const int kbyt = ((lane >> 4) << 4) + kk * 64;       // byte offset in row
            const int kswz = kbyt ^ ((r16 & 7) << 4);            // LDS XOR swizzle
            bf16x8 af[4], bfr[4];
            #pragma unroll
            for (int i = 0; i < 4; i++) {
                const int row = wr * 64 + i * 16 + r16;
                af[i] = *(const bf16x8*)((const char*)lA + row * 128 + kswz);
            }
            #pragma unroll
            for (int j = 0; j < 4; j++) {
                const int row = wc * 64 + j * 16 + r16;
                bfr[j] = *(const bf16x8*)((const char*)lB + row * 128 + kswz);
            }
            #pragma unroll
            for (int i = 0; i < 4; i++)
                #pragma unroll
                for (int j = 0; j < 4; j++)
                    acc[i][j] = __builtin_amdgcn_mfma_f32_16x16x32_bf16(
                        af[i], bfr[j], acc[i][j], 0, 0, 0);
        }
    }

    // epilogue: bias + sigmoid, write fp32.  C/D layout: col=lane&15,
    // row=(lane>>4)*4+reg  [measured m89/m91]
    const float* bias = (n0 < 512) ? bq : ((n0 < 1024) ? bs : bk);
    float* obase = out + (size_t)(n0 >> 9) * ((size_t)BATCH_N * 512);
    const int nb = n0 & 511;
    #pragma unroll
    for (int j = 0; j < 4; j++) {
        const int col = nb + wc * 64 + j * 16 + (lane & 15);
        const float bv = bias[col];
        #pragma unroll
        for (int i = 0; i < 4; i++) {
            const int rbase = m0 + wr * 64 + i * 16 + ((lane >> 4) << 2);
            #pragma unroll
            for (int r = 0; r < 4; r++) {
                float v = acc[i][j][r] + bv;
                v = 1.0f / (1.0f + __expf(-v));
                obase[(size_t)(rbase + r) * 512 + col] = v;
            }
        }
    }
}

extern "C" void kernel_launch(void* const* d_in, const int* in_sizes, int n_in,
                              void* d_out, int out_size, void* d_ws, size_t ws_size,
                              hipStream_t stream) {
    const int*   ids = (const int*)d_in[0];
    const float* mem = (const float*)d_in[1];
    const float* emb = (const float*)d_in[2];
    const float* Wq  = (const float*)d_in[3];
    const float* bq  = (const float*)d_in[4];
    const float* Ws  = (const float*)d_in[5];
    const float* bs  = (const float*)d_in[6];
    const float* Wk  = (const float*)d_in[7];
    const float* bk  = (const float*)d_in[8];
    float* out = (float*)d_out;

    unsigned short* x  = (unsigned short*)d_ws;              // 65536*1024 bf16 = 128 MiB
    unsigned short* wt = x + (size_t)BATCH_N * KDIM;         // 1536*1024  bf16 = 3 MiB

    hipLaunchKernelGGL(wconv_kernel, dim3(NTOT), dim3(256), 0, stream, Wq, Ws, Wk, wt);
    hipLaunchKernelGGL(prep_kernel, dim3(BATCH_N), dim3(256), 0, stream, ids, mem, emb, x);
    hipLaunchKernelGGL(gemm_kernel, dim3(512 * 12), dim3(256), 0, stream,
                       x, wt, bq, bs, bk, out);
}

// Round 2
// 415.310 us; speedup vs baseline: 1.0818x; 1.0818x over previous
//
#include <hip/hip_runtime.h>
#include <hip/hip_bf16.h>
#include <stdint.h>

#define BATCH_N 65536
#define KDIM 1024
#define NTOT 1536

typedef __bf16 bf16x8 __attribute__((ext_vector_type(8)));
typedef float f32x4 __attribute__((ext_vector_type(4)));

__device__ __forceinline__ unsigned short f2bf(float f) {
    unsigned u = __builtin_bit_cast(unsigned, f);
    u += 0x7FFFu + ((u >> 16) & 1u);   // round-to-nearest-even
    return (unsigned short)(u >> 16);
}

// ---------------------------------------------------------------------------
// Kernel 1: x[b][k] = sum_k(node_memories[id]) + node_embedding[id][k], bf16,
// stored pre-swizzled (k ^= (b&7)<<3) so linear global_load_lds staging in the
// GEMM produces a bank-conflict-free LDS layout.
// ---------------------------------------------------------------------------
__global__ __launch_bounds__(256) void prep_kernel(
    const int* __restrict__ ids,
    const float* __restrict__ mem,
    const float* __restrict__ emb,
    unsigned short* __restrict__ x)
{
    const int b = blockIdx.x;
    const int t = threadIdx.x;
    const int id = ids[b];
    const float4* m4 = (const float4*)(mem + (size_t)id * KDIM);
    const float4* e4 = (const float4*)(emb + (size_t)id * KDIM);
    float4 v = m4[t];
    float s = v.x + v.y + v.z + v.w;
    #pragma unroll
    for (int off = 32; off >= 1; off >>= 1) s += __shfl_down(s, off, 64);
    __shared__ float wsum[4];
    const int lane = t & 63, w = t >> 6;
    if (lane == 0) wsum[w] = s;
    __syncthreads();
    const float tot = wsum[0] + wsum[1] + wsum[2] + wsum[3];
    float4 e = e4[t];
    ushort4 o;
    o.x = f2bf(tot + e.x);
    o.y = f2bf(tot + e.y);
    o.z = f2bf(tot + e.z);
    o.w = f2bf(tot + e.w);
    const int k   = t * 4;
    const int ksw = k ^ ((b & 7) << 3);
    *(ushort4*)(x + (size_t)b * KDIM + ksw) = o;
}

// ---------------------------------------------------------------------------
// Kernel 2: Wt[n][k] = W_{n/512}[k][n%512] in bf16, same pre-swizzle on k.
// ---------------------------------------------------------------------------
__global__ __launch_bounds__(256) void wconv_kernel(
    const float* __restrict__ Wq, const float* __restrict__ Ws,
    const float* __restrict__ Wk, unsigned short* __restrict__ wt)
{
    const int gt = blockIdx.x * 256 + threadIdx.x;   // 0..393215
    const int n  = gt % NTOT;
    const int kb = (gt / NTOT) * 4;
    const float* W = (n < 512) ? Wq : ((n < 1024) ? Ws : Wk);
    const int nn = n & 511;
    ushort4 o;
    o.x = f2bf(W[(size_t)(kb + 0) * 512 + nn]);
    o.y = f2bf(W[(size_t)(kb + 1) * 512 + nn]);
    o.z = f2bf(W[(size_t)(kb + 2) * 512 + nn]);
    o.w = f2bf(W[(size_t)(kb + 3) * 512 + nn]);
    const int ksw = kb ^ ((n & 7) << 3);
    *(ushort4*)(wt + (size_t)n * KDIM + ksw) = o;
}

// ---------------------------------------------------------------------------
// Kernel 3: C[m][n] = sigmoid(x @ W + b), 128x128 tile, BK=64, 4 waves,
// mfma_f32_16x16x32_bf16, global_load_lds(16B) staging, swizzled LDS.
// Grid: nt fastest within a contiguous per-XCD band (bijective swizzle) so
// the 12 n-tiles sharing one A-tile run back-to-back on the same XCD (L2
// reuse of A), and the whole 3 MB W stays L2-resident per XCD.
// ---------------------------------------------------------------------------
#define BM 128
#define BN 128
#define BK 64
#define MT 512                    // 65536 / BM
#define NT 12                     // 1536 / BN
#define NWG (MT * NT)             // 6144 = 8 * 768, 768 % 12 == 0 -> bijective

__global__ __launch_bounds__(256, 2) void gemm_kernel(
    const unsigned short* __restrict__ X,    // [65536][1024] bf16, swizzled
    const unsigned short* __restrict__ Wt,   // [1536][1024]  bf16, swizzled
    const float* __restrict__ bq, const float* __restrict__ bs,
    const float* __restrict__ bk, float* __restrict__ out)
{
    __shared__ __align__(16) unsigned short lA[BM * BK];  // 16 KiB
    __shared__ __align__(16) unsigned short lB[BN * BK];  // 16 KiB

    const int tid  = threadIdx.x;
    // XCD-bijective swizzle: 8 contiguous chunks of 768 blocks each
    const int xcd  = blockIdx.x & 7;
    const int idx  = blockIdx.x >> 3;
    const int wgid = xcd * (NWG / 8) + idx;
    const int nt   = wgid % NT;              // n fastest: A-tile L2 reuse
    const int mt   = wgid / NT;
    const int m0   = mt * BM;
    const int n0   = nt * BN;
    const int wid  = tid >> 6;
    const int lane = tid & 63;
    const int wr   = wid >> 1, wc = wid & 1;

    f32x4 acc[4][4];
    #pragma unroll
    for (int i = 0; i < 4; i++)
        #pragma unroll
        for (int j = 0; j < 4; j++)
            acc[i][j] = f32x4{0.f, 0.f, 0.f, 0.f};

    const unsigned short* gA = X  + (size_t)(m0 + (tid >> 3)) * KDIM + (size_t)(tid & 7) * 8;
    const unsigned short* gB = Wt + (size_t)(n0 + (tid >> 3)) * KDIM + (size_t)(tid & 7) * 8;

    for (int ks = 0; ks < KDIM; ks += BK) {
        __syncthreads();
        #pragma unroll
        for (int i = 0; i < 4; i++) {
            __builtin_amdgcn_global_load_lds(
                (const __attribute__((address_space(1))) void*)(gA + (size_t)i * 32 * KDIM + ks),
                (__attribute__((address_space(3))) void*)(&lA[(i * 256 + (tid & 192)) * 8]),
                16, 0, 0);
        }
        #pragma unroll
        for (int i = 0; i < 4; i++) {
            __builtin_amdgcn_global_load_lds(
                (const __attribute__((address_space(1))) void*)(gB + (size_t)i * 32 * KDIM + ks),
                (__attribute__((address_space(3))) void*)(&lB[(i * 256 + (tid & 192)) * 8]),
                16, 0, 0);
        }
        __syncthreads();

        #pragma unroll
        for (int kk = 0; kk < 2; kk++) {
            const int r16  = lane & 15;
            const int kbyt = ((lane >> 4) << 4) + kk * 64;       // byte offset in row
            const int kswz = kbyt ^ ((r16 & 7) << 4);            // LDS XOR swizzle
            bf16x8 af[4], bfr[4];
            #pragma unroll
            for (int i = 0; i < 4; i++) {
                const int row = wr * 64 + i * 16 + r16;
                af[i] = *(const bf16x8*)((const char*)lA + row * 128 + kswz);
            }
            #pragma unroll
            for (int j = 0; j < 4; j++) {
                const int row = wc * 64 + j * 16 + r16;
                bfr[j] = *(const bf16x8*)((const char*)lB + row * 128 + kswz);
            }
            #pragma unroll
            for (int i = 0; i < 4; i++)
                #pragma unroll
                for (int j = 0; j < 4; j++)
                    acc[i][j] = __builtin_amdgcn_mfma_f32_16x16x32_bf16(
                        af[i], bfr[j], acc[i][j], 0, 0, 0);
        }
    }

    // epilogue: bias + sigmoid, nontemporal fp32 stores (write-once stream —
    // keep L2/L3 for X and W).  C/D layout: col=lane&15, row=(lane>>4)*4+reg
    const float* bias = (n0 < 512) ? bq : ((n0 < 1024) ? bs : bk);
    float* obase = out + (size_t)(n0 >> 9) * ((size_t)BATCH_N * 512);
    const int nb = n0 & 511;
    #pragma unroll
    for (int j = 0; j < 4; j++) {
        const int col = nb + wc * 64 + j * 16 + (lane & 15);
        const float bv = bias[col];
        #pragma unroll
        for (int i = 0; i < 4; i++) {
            const int rbase = m0 + wr * 64 + i * 16 + ((lane >> 4) << 2);
            #pragma unroll
            for (int r = 0; r < 4; r++) {
                float v = acc[i][j][r] + bv;
                v = 1.0f / (1.0f + __expf(-v));
                __builtin_nontemporal_store(v, &obase[(size_t)(rbase + r) * 512 + col]);
            }
        }
    }
}

extern "C" void kernel_launch(void* const* d_in, const int* in_sizes, int n_in,
                              void* d_out, int out_size, void* d_ws, size_t ws_size,
                              hipStream_t stream) {
    const int*   ids = (const int*)d_in[0];
    const float* mem = (const float*)d_in[1];
    const float* emb = (const float*)d_in[2];
    const float* Wq  = (const float*)d_in[3];
    const float* bq  = (const float*)d_in[4];
    const float* Ws  = (const float*)d_in[5];
    const float* bs  = (const float*)d_in[6];
    const float* Wk  = (const float*)d_in[7];
    const float* bk  = (const float*)d_in[8];
    float* out = (float*)d_out;

    unsigned short* x  = (unsigned short*)d_ws;              // 65536*1024 bf16 = 128 MiB
    unsigned short* wt = x + (size_t)BATCH_N * KDIM;         // 1536*1024  bf16 = 3 MiB

    hipLaunchKernelGGL(wconv_kernel, dim3(NTOT), dim3(256), 0, stream, Wq, Ws, Wk, wt);
    hipLaunchKernelGGL(prep_kernel, dim3(BATCH_N), dim3(256), 0, stream, ids, mem, emb, x);
    hipLaunchKernelGGL(gemm_kernel, dim3(NWG), dim3(256), 0, stream,
                       x, wt, bq, bs, bk, out);
}